// Round 3
// baseline (381.330 us; speedup 1.0000x reference)
//
#include <hip/hip_runtime.h>

// Causal attention head: B=4, T=2048, C=1024, fp32 in/out.
//   k = x@Wk^T, q = x@Wq^T, v = x@Wv^T ; S = q@k^T (no scale, causal) ;
//   P = softmax(S) ; out = P@v
//
// R3 changes vs R2 (counter-driven; R2: conflicts=0 but MfmaUtil 31%, occ 13%):
//  - K-virtualized streams: per K-block (pointer,offset) table stages ONE
//    (A-part,B-part) pair -> LDS 64KB->32KB -> 4-5 blocks/CU (was 2).
//    Same MFMA count; drains now hide across co-resident blocks (m114).
//  - q/k/v projections fused into ONE launch (grid 1536 = 64 rows x 24 cols)
//    so 4+/CU residency is actually reachable.
//  - v-projection 1-pass bf16 (error ~9e-4, no logit amplification) and
//    PV 1-pass (P bf16 x vt bf16): 7 passes instead of 9 (proj), 1 not 2 (PV).
//  - q/k/S stay 3-pass split-bf16 (softmax logits sigma~10.7 need ~15 bits).
//
// Workspace layout (byte offsets; lifetime overlays; 144 MiB used):
//   [0,        67108864)  S fp32 [4][2048][2048]   (written AFTER W+x are dead)
//     [0,      12582912)   W splits: wkhi,wklo,wqhi,wqlo,wvhi,wvlo (2 MiB each)
//     [12582912,46137344)  xhi, xlo (16 MiB each)
//   [67108864, 134217728) qhi,qlo,khi,klo (16 MiB each)
//     [67108864,100663296) P bf16 [4][2048][2048]  (overlays q after S-GEMM done)
//   [134217728,150994944) vthi [4][1024][2048] (16 MiB)

#define GLOBAL_AS __attribute__((address_space(1)))
#define LDS_AS    __attribute__((address_space(3)))

typedef __attribute__((ext_vector_type(8))) short short8;
typedef __attribute__((ext_vector_type(4))) float f32x4;
typedef long long ll;

__device__ __forceinline__ unsigned short f2bf(float f) {
  unsigned u = __float_as_uint(f);
  u += 0x7FFFu + ((u >> 16) & 1u);   // RTNE (finite values only here)
  return (unsigned short)(u >> 16);
}
__device__ __forceinline__ float bf2f(unsigned short s) {
  return __uint_as_float((unsigned)s << 16);
}

__device__ __forceinline__ void gload_lds16(const unsigned short* g, unsigned short* l) {
  __builtin_amdgcn_global_load_lds((const GLOBAL_AS unsigned int*)g,
                                   (LDS_AS unsigned int*)l, 16, 0, 0);
}

// ---------------- fp32 -> (bf16 hi, bf16 lo) split conversion -----------------
__global__ __launch_bounds__(256) void split_f32_kernel(
    const float* __restrict__ src, unsigned short* __restrict__ hi,
    unsigned short* __restrict__ lo, int n8) {
  int i = blockIdx.x * 256 + threadIdx.x;
  if (i >= n8) return;
  const float4* s4 = (const float4*)src;
  float4 a = s4[2 * i], c = s4[2 * i + 1];
  float v[8] = {a.x, a.y, a.z, a.w, c.x, c.y, c.z, c.w};
  unsigned hw[4], lw[4];
#pragma unroll
  for (int j = 0; j < 4; ++j) {
    unsigned short h0 = f2bf(v[2 * j]),     h1 = f2bf(v[2 * j + 1]);
    unsigned short l0 = f2bf(v[2 * j] - bf2f(h0));
    unsigned short l1 = f2bf(v[2 * j + 1] - bf2f(h1));
    hw[j] = (unsigned)h0 | ((unsigned)h1 << 16);
    lw[j] = (unsigned)l0 | ((unsigned)l1 << 16);
  }
  *(uint4*)(hi + 8 * i) = make_uint4(hw[0], hw[1], hw[2], hw[3]);
  *(uint4*)(lo + 8 * i) = make_uint4(lw[0], lw[1], lw[2], lw[3]);
}

// ------------- K-virtualized 128x128-tile A·B^T GEMM (m97-shape loop) ---------
// 256 thr = 4 waves, wave tile 64x64 = 4x4 frags of 16x16, BK=64.
// Per virtual K-block kb: pass p = kb>>4, k0 = (kb&15)*64 -> stage ONE
// (A-part, B-part) 128x64 pair (32 KB LDS total, single-buffered), 32 MFMA.
// LDS swizzle: 16B chunk j of row r stored at slot j^(r&7) via pre-swizzled
// global source (global_load_lds dest stays linear); same XOR on ds_read.
// MODE 0 = fused qkv projection: A=x splits, B selected by col-tile among
//          {Wq,Wk,Wv}; q/k 3 passes -> split-bf16 out; v 1 pass -> vT bf16.
// MODE 1 = S = q k^T: 3 passes, triangular tile list, fp32 out.
// MODE 2 = out = P vT^T: 1 pass, kEnd=(ti+1)*128, fp32 out.
template <int MODE>
__global__ __launch_bounds__(256, 4) void gemm_kv(
    const unsigned short* __restrict__ A0, const unsigned short* __restrict__ A1,
    int lda, ll strA,
    const unsigned short* __restrict__ B0, const unsigned short* __restrict__ B1,
    const unsigned short* __restrict__ B2, const unsigned short* __restrict__ B3,
    const unsigned short* __restrict__ B4,
    int ldb, ll strB,
    void* __restrict__ C0, void* __restrict__ C1, void* __restrict__ C2,
    void* __restrict__ C3, void* __restrict__ C4, int ldc, ll strC, int ntc) {
  __shared__ __align__(16) unsigned short lds[2 * 128 * 64];
  unsigned short* LA = lds;
  unsigned short* LB = lds + 128 * 64;

  // T1: XCD-chunked swizzle (grid.x % 8 == 0 for all our launches)
  const int bx0 = blockIdx.x;
  const int bx = ((gridDim.x & 7) == 0) ? ((bx0 & 7) * (gridDim.x >> 3) + (bx0 >> 3)) : bx0;
  const int b = blockIdx.y;
  int ti, tj;
  if constexpr (MODE == 1) {  // linear idx -> (ti, tj), tj<=ti
    int rem = bx, i = 0;
    while (rem > i) { rem -= (i + 1); ++i; }
    ti = i; tj = rem;
  } else {
    ti = bx / ntc; tj = bx - ti * ntc;
  }
  const int row0 = ti << 7;

  // ----- per-mode operand bases and virtual-K extent -----
  const unsigned short *aH, *aL, *bH, *bL;
  int nkb;
  int which = 0, colw = 0;  // MODE 0: which W (0=q,1=k,2=v), col within W
  if constexpr (MODE == 0) {
    which = tj >> 3; colw = (tj & 7) << 7;
    aH = A0 + (ll)row0 * lda; aL = A1 + (ll)row0 * lda;
    if (which == 0)      { bH = B0; bL = B1; }
    else if (which == 1) { bH = B2; bL = B3; }
    else                 { bH = B4; bL = B4; }
    bH += (ll)colw * ldb; bL += (ll)colw * ldb;
    nkb = (which == 2) ? 16 : 48;
  } else if constexpr (MODE == 1) {
    aH = A0 + (ll)b * strA + (ll)row0 * lda; aL = A1 + (ll)b * strA + (ll)row0 * lda;
    bH = B0 + (ll)b * strB + (ll)(tj << 7) * ldb; bL = B1 + (ll)b * strB + (ll)(tj << 7) * ldb;
    nkb = 48;
  } else {
    aH = A0 + (ll)b * strA + (ll)row0 * lda; aL = aH;
    bH = B0 + (ll)b * strB + (ll)(tj << 7) * ldb; bL = bH;
    nkb = (ti + 1) << 1;
  }

  const int t = threadIdx.x;
  const int lane = t & 63, w = t >> 6;
  const int wr = (w >> 1) << 6, wc = (w & 1) << 6;
  const int fr = lane & 15, fg = lane >> 4;

  f32x4 acc[4][4];
#pragma unroll
  for (int m = 0; m < 4; ++m)
#pragma unroll
    for (int n = 0; n < 4; ++n) acc[m][n] = (f32x4){0.f, 0.f, 0.f, 0.f};

  for (int kb = 0; kb < nkb; ++kb) {
    int p, k0;
    if constexpr (MODE == 2) { p = 0; k0 = kb << 6; }
    else                     { p = kb >> 4; k0 = (kb & 15) << 6; }
    const unsigned short* pA = (p == 2) ? aL : aH;
    const unsigned short* pB = (p == 1) ? bL : bH;
    // ---- stage one (A,B) pair; LDS dest linear, source chunk XOR-swizzled ----
#pragma unroll
    for (int c = 0; c < 4; ++c) {
      const int lin = c * 256 + t;
      const int r = lin >> 3;
      const int js = (lin & 7) ^ (r & 7);
      gload_lds16(pA + (ll)r * lda + k0 + js * 8, LA + lin * 8);
      gload_lds16(pB + (ll)r * ldb + k0 + js * 8, LB + lin * 8);
    }
    __syncthreads();  // vmcnt(0) drain (compiler) -> LDS ready
#pragma unroll
    for (int ks = 0; ks < 2; ++ks) {
      short8 a[4];
#pragma unroll
      for (int m = 0; m < 4; ++m) {
        const int row = wr + m * 16 + fr;
        const int cj = (ks * 4 + fg) ^ (row & 7);
        a[m] = *(const short8*)(LA + row * 64 + cj * 8);
      }
#pragma unroll
      for (int n = 0; n < 4; ++n) {
        const int row = wc + n * 16 + fr;
        const int cj = (ks * 4 + fg) ^ (row & 7);
        const short8 bfrag = *(const short8*)(LB + row * 64 + cj * 8);
#pragma unroll
        for (int m = 0; m < 4; ++m)
          acc[m][n] = __builtin_amdgcn_mfma_f32_16x16x32_bf16(a[m], bfrag, acc[m][n], 0, 0, 0);
      }
    }
    __syncthreads();  // protect LDS before next stage
  }

  // ---- epilogue: D layout col=lane&15, row=(lane>>4)*4+j [m89-verified] ----
#pragma unroll
  for (int m = 0; m < 4; ++m)
#pragma unroll
    for (int n = 0; n < 4; ++n)
#pragma unroll
      for (int j = 0; j < 4; ++j) {
        const int r = row0 + wr + m * 16 + fg * 4 + j;
        const int cl = wc + n * 16 + fr;  // col within tile
        const float v = acc[m][n][j];
        if constexpr (MODE == 0) {
          if (which == 2) {  // vT[b][d][t] bf16 (hi only)
            const int bb = r >> 11, tt = r & 2047;
            ((unsigned short*)C4)[(ll)bb * (1024LL * 2048) + (ll)(colw + cl) * 2048 + tt] = f2bf(v);
          } else {           // split bf16 q or k: [r*1024 + col]
            unsigned short* hi = (unsigned short*)(which == 0 ? C0 : C2);
            unsigned short* lo = (unsigned short*)(which == 0 ? C1 : C3);
            const ll addr = (ll)r * 1024 + colw + cl;
            const unsigned short h = f2bf(v);
            hi[addr] = h;
            lo[addr] = f2bf(v - bf2f(h));
          }
        } else {  // fp32 C0[b*strC + r*ldc + c]
          ((float*)C0)[(ll)b * strC + (ll)r * ldc + ((tj << 7) + cl)] = v;
        }
      }
}

// ---------------- causal row softmax: S fp32 -> P bf16 (zero-filled) ----------
__global__ __launch_bounds__(256) void softmax_causal_kernel(
    const float* __restrict__ S, unsigned short* __restrict__ P) {
  __shared__ float red[8];
  const int tq = blockIdx.x;  // row 0..2047
  const int b = blockIdx.y;
  const float* s = S + (ll)b * 2048 * 2048 + (ll)tq * 2048;
  unsigned short* p = P + (ll)b * 2048 * 2048 + (ll)tq * 2048;
  const int n = tq + 1;  // valid cols (cols > tq are poison: never read)
  const int t = threadIdx.x;

  float vals[8];
  float mx = -1e30f;
#pragma unroll
  for (int c = 0; c < 8; ++c) {
    const int i = t + c * 256;
    if (i < n) { vals[c] = s[i]; mx = fmaxf(mx, vals[c]); }
  }
#pragma unroll
  for (int o = 32; o > 0; o >>= 1) mx = fmaxf(mx, __shfl_xor(mx, o, 64));
  if ((t & 63) == 0) red[t >> 6] = mx;
  __syncthreads();
  mx = fmaxf(fmaxf(red[0], red[1]), fmaxf(red[2], red[3]));

  float sum = 0.f;
#pragma unroll
  for (int c = 0; c < 8; ++c) {
    const int i = t + c * 256;
    if (i < n) { const float e = __expf(vals[c] - mx); vals[c] = e; sum += e; }
  }
#pragma unroll
  for (int o = 32; o > 0; o >>= 1) sum += __shfl_xor(sum, o, 64);
  if ((t & 63) == 0) red[4 + (t >> 6)] = sum;
  __syncthreads();
  sum = (red[4] + red[5]) + (red[6] + red[7]);
  const float inv = 1.0f / sum;
#pragma unroll
  for (int c = 0; c < 8; ++c) {
    const int i = t + c * 256;
    if (i < n) p[i] = f2bf(vals[c] * inv);
  }
  for (int ii = t; ii < 2048; ii += 256)
    if (ii >= n) p[ii] = 0;  // zero-fill masked cols so PV can read full K rows
}

// -------------------------------- launch --------------------------------------
extern "C" void kernel_launch(void* const* d_in, const int* in_sizes, int n_in,
                              void* d_out, int out_size, void* d_ws, size_t ws_size,
                              hipStream_t stream) {
  (void)in_sizes; (void)n_in; (void)out_size; (void)ws_size;
  const float* x  = (const float*)d_in[0];
  const float* Wk = (const float*)d_in[1];  // NOTE input order: x, Wk, Wq, Wv
  const float* Wq = (const float*)d_in[2];
  const float* Wv = (const float*)d_in[3];
  char* ws = (char*)d_ws;

  float*          Sbuf = (float*)ws;                              // 64 MiB
  unsigned short* wkhi = (unsigned short*)(ws + 0);
  unsigned short* wklo = (unsigned short*)(ws + 2097152);
  unsigned short* wqhi = (unsigned short*)(ws + 4194304);
  unsigned short* wqlo = (unsigned short*)(ws + 6291456);
  unsigned short* wvhi = (unsigned short*)(ws + 8388608);
  unsigned short* wvlo = (unsigned short*)(ws + 10485760);
  unsigned short* xhi  = (unsigned short*)(ws + 12582912);
  unsigned short* xlo  = (unsigned short*)(ws + 29360128);
  unsigned short* qhi  = (unsigned short*)(ws + 67108864);
  unsigned short* qlo  = (unsigned short*)(ws + 83886080);
  unsigned short* khi  = (unsigned short*)(ws + 100663296);
  unsigned short* klo  = (unsigned short*)(ws + 117440512);
  unsigned short* Pbuf = (unsigned short*)(ws + 67108864);        // overlays q
  unsigned short* vthi = (unsigned short*)(ws + 134217728);

  // 1) split conversions (Wv's lo half is converted but unused)
  split_f32_kernel<<<4096, 256, 0, stream>>>(x, xhi, xlo, 1048576);
  split_f32_kernel<<<512, 256, 0, stream>>>(Wq, wqhi, wqlo, 131072);
  split_f32_kernel<<<512, 256, 0, stream>>>(Wk, wkhi, wklo, 131072);
  split_f32_kernel<<<512, 256, 0, stream>>>(Wv, wvhi, wvlo, 131072);

  // 2) fused qkv projection: M=8192, 24 col-tiles (8 q | 8 k | 8 v), grid 1536
  gemm_kv<0><<<dim3(1536, 1), 256, 0, stream>>>(
      xhi, xlo, 1024, 0,
      wqhi, wqlo, wkhi, wklo, wvhi, 1024, 0,
      qhi, qlo, khi, klo, vthi, 1024, 0, 24);

  // 3) S = q k^T, causal triangular tile grid (136 tiles x 4 batches)
  gemm_kv<1><<<dim3(136, 4), 256, 0, stream>>>(
      qhi, qlo, 1024, 2048LL * 1024,
      khi, klo, nullptr, nullptr, nullptr, 1024, 2048LL * 1024,
      Sbuf, nullptr, nullptr, nullptr, nullptr, 2048, 2048LL * 2048, 8);

  // 4) causal softmax -> P (bf16, zero-filled above diagonal)
  softmax_causal_kernel<<<dim3(2048, 4), 256, 0, stream>>>(Sbuf, Pbuf);

  // 5) out = P vT^T: M=2048, N=1024, kEnd=(ti+1)*128, grid 128 x 4
  gemm_kv<2><<<dim3(128, 4), 256, 0, stream>>>(
      Pbuf, nullptr, 2048, 2048LL * 2048,
      vthi, nullptr, nullptr, nullptr, nullptr, 2048, 1024LL * 2048,
      d_out, nullptr, nullptr, nullptr, nullptr, 1024, 2048LL * 1024, 8);
}